// Round 3
// baseline (460.583 us; speedup 1.0000x reference)
//
#include <hip/hip_runtime.h>
#include <stdint.h>

#define NN 4096
#define NITER 10
#define ROWS 16        // rows per iterate block
#define NBLK (NN / ROWS)   // 256 iterate blocks

__device__ __forceinline__ float bf2f(unsigned short u) {
  union { unsigned int i; float f; } x; x.i = ((unsigned int)u) << 16; return x.f;
}
__device__ __forceinline__ unsigned short f2bf(float f) {
  union { float f; unsigned int i; } x; x.f = f;
  unsigned int i = x.i;
  i += 0x7FFFu + ((i >> 16) & 1u);   // round-to-nearest-even
  return (unsigned short)(i >> 16);
}
__device__ __forceinline__ float2 unpk(unsigned int u) {
  union { unsigned int i; float f; } a, b;
  a.i = u << 16; b.i = u & 0xFFFF0000u;
  return make_float2(a.f, b.f);
}
__device__ __forceinline__ float read_eps(const void* p) {
  float f = *(const float*)p;
  if (f > 1e-4f && f < 1.0f) return f;
  union { unsigned int i; float f; } x; x.i = ((unsigned int)*(const unsigned short*)p) << 16;
  return x.f;
}

// ---------------------------------------------------------------------------
// K[i] = exp(-C[i]/eps) stored bf16; also init v_t[m][s] = 1
__global__ __launch_bounds__(256) void build_k(
    const float* __restrict__ C, const void* __restrict__ epsp,
    unsigned short* __restrict__ K, float* __restrict__ v_t) {
  int gid = blockIdx.x * 256 + threadIdx.x;
  float nie = -1.0f / read_eps(epsp);
  float4 c0 = ((const float4*)C)[gid * 2];
  float4 c1 = ((const float4*)C)[gid * 2 + 1];
  float e[8];
  e[0] = __expf(c0.x * nie); e[1] = __expf(c0.y * nie);
  e[2] = __expf(c0.z * nie); e[3] = __expf(c0.w * nie);
  e[4] = __expf(c1.x * nie); e[5] = __expf(c1.y * nie);
  e[6] = __expf(c1.z * nie); e[7] = __expf(c1.w * nie);
  uint4 o;
  o.x = (unsigned int)f2bf(e[0]) | ((unsigned int)f2bf(e[1]) << 16);
  o.y = (unsigned int)f2bf(e[2]) | ((unsigned int)f2bf(e[3]) << 16);
  o.z = (unsigned int)f2bf(e[4]) | ((unsigned int)f2bf(e[5]) << 16);
  o.w = (unsigned int)f2bf(e[6]) | ((unsigned int)f2bf(e[7]) << 16);
  ((uint4*)K)[gid] = o;
  if (gid < NN) ((float4*)v_t)[gid] = make_float4(1.f, 1.f, 1.f, 1.f);
}

// ---------------------------------------------------------------------------
// Fused per-iteration kernel. Block b owns rows [b*16, b*16+16).
//  pass 0: stage v_t (4096 x float4) into LDS, xor-swizzled (slot = m ^ ((m>>3)&7))
//  pass 1: rowsum[n][s] = sum_m K[n][m]*v[m][s] (4 rows/wave, lanes span cols);
//          u[n][s] = alpha[s][n]/rowsum -> LDS overlay + global u_t
//  pass 2: col-partials: partial[b][m][s] = sum_{n in block} K[n][m]*u[n][s]
//          (thread owns 16 cols, K re-read is L2-hot)
__global__ __launch_bounds__(256) void iterate(
    const unsigned short* __restrict__ K, const float* __restrict__ v_t,
    const float* __restrict__ alpha, float* __restrict__ u_t,
    float* __restrict__ partial) {
  __shared__ float v_lds[NN * 4];   // 64 KiB; slots 0..15 reused for u after pass 1
  int t = threadIdx.x;
  int wave = t >> 6, lane = t & 63;
  int sw = lane & 7;
  int row0 = blockIdx.x * ROWS;

  // ---- pass 0: stage v (swizzled float4 slots) ----
  {
    const float4* V = (const float4*)v_t;
    float4* L = (float4*)v_lds;
#pragma unroll
    for (int k = 0; k < 16; ++k) {
      int idx = t + k * 256;
      L[idx ^ ((idx >> 3) & 7)] = V[idx];
    }
  }
  __syncthreads();

  // ---- pass 1: row dots, 4 rows per wave ----
  float acc[4][4] = {};
  int r0 = row0 + wave * 4;
  const uint4* Kr0 = (const uint4*)(K + (size_t)r0 * NN);  // row stride = 512 uint4
  const float4* VL = (const float4*)v_lds;
#pragma unroll 2
  for (int mb = 0; mb < 8; ++mb) {
    int m0 = mb * 512 + lane * 8;
    uint4 karr[4];
    karr[0] = Kr0[(m0 >> 3)];
    karr[1] = Kr0[(m0 >> 3) + 512];
    karr[2] = Kr0[(m0 >> 3) + 1024];
    karr[3] = Kr0[(m0 >> 3) + 1536];
    float4 vv[8];
#pragma unroll
    for (int j = 0; j < 8; ++j) vv[j] = VL[m0 + (j ^ sw)];
    // vv[j^sw] is column m0+j... invert: column of vv slot (j^sw) is m0+j.
    // Equivalent: vv_col[j] = VL[m0 + (j^sw)] where stored slot s=m^((m>>3)&7);
    // for m=m0+j, (m>>3)&7 == lane&7 == sw, so slot = m0 + (j^sw). vv[j] IS column m0+j. OK.
#pragma unroll
    for (int r = 0; r < 4; ++r) {
      unsigned int cw[4] = {karr[r].x, karr[r].y, karr[r].z, karr[r].w};
#pragma unroll
      for (int w = 0; w < 4; ++w) {
        float2 f = unpk(cw[w]);
        float4 va = vv[2 * w], vb = vv[2 * w + 1];
        acc[r][0] += f.x * va.x; acc[r][1] += f.x * va.y;
        acc[r][2] += f.x * va.z; acc[r][3] += f.x * va.w;
        acc[r][0] += f.y * vb.x; acc[r][1] += f.y * vb.y;
        acc[r][2] += f.y * vb.z; acc[r][3] += f.y * vb.w;
      }
    }
  }
  // butterfly reduce across 64 lanes
#pragma unroll
  for (int off = 32; off > 0; off >>= 1)
#pragma unroll
    for (int r = 0; r < 4; ++r)
#pragma unroll
      for (int s = 0; s < 4; ++s)
        acc[r][s] += __shfl_xor(acc[r][s], off);
  __syncthreads();   // all v reads done; safe to overlay u into v_lds
  if (lane < 16) {
    int rl = lane >> 2, s = lane & 3;
    int myrow = r0 + rl;
    float uval = alpha[s * NN + myrow] / acc[rl][s];
    v_lds[wave * 16 + lane] = uval;   // float idx = (wave*4+rl)*4+s
    u_t[myrow * 4 + s] = uval;
  }
  __syncthreads();

  // ---- pass 2: column partials, thread owns 16 cols ----
  float a2[16][4] = {};
  const unsigned short* Kc = K + (size_t)row0 * NN + t * 16;
#pragma unroll 4
  for (int n = 0; n < ROWS; ++n) {
    float4 u4 = ((const float4*)v_lds)[n];   // broadcast
    const uint4* kp = (const uint4*)(Kc + (size_t)n * NN);
    uint4 ka = kp[0], kb = kp[1];
    unsigned int aw[4] = {ka.x, ka.y, ka.z, ka.w};
    unsigned int bw[4] = {kb.x, kb.y, kb.z, kb.w};
#pragma unroll
    for (int w = 0; w < 4; ++w) {
      float2 fa = unpk(aw[w]);
      a2[2*w][0]   += fa.x * u4.x; a2[2*w][1]   += fa.x * u4.y;
      a2[2*w][2]   += fa.x * u4.z; a2[2*w][3]   += fa.x * u4.w;
      a2[2*w+1][0] += fa.y * u4.x; a2[2*w+1][1] += fa.y * u4.y;
      a2[2*w+1][2] += fa.y * u4.z; a2[2*w+1][3] += fa.y * u4.w;
      float2 fb = unpk(bw[w]);
      a2[8+2*w][0]   += fb.x * u4.x; a2[8+2*w][1]   += fb.x * u4.y;
      a2[8+2*w][2]   += fb.x * u4.z; a2[8+2*w][3]   += fb.x * u4.w;
      a2[9+2*w][0]   += fb.y * u4.x; a2[9+2*w][1]   += fb.y * u4.y;
      a2[9+2*w][2]   += fb.y * u4.z; a2[9+2*w][3]   += fb.y * u4.w;
    }
  }
  float4* P = (float4*)partial + (size_t)blockIdx.x * NN + t * 16;
#pragma unroll
  for (int j = 0; j < 16; ++j)
    P[j] = make_float4(a2[j][0], a2[j][1], a2[j][2], a2[j][3]);
}

// ---------------------------------------------------------------------------
// v_t[m][s] = beta[s][m] / sum_b partial[b][m][s]
// 64 blocks x 256; block owns 64 m's; 4 groups of 64 b's per thread-row
__global__ __launch_bounds__(256) void reduceV(
    const float* __restrict__ partial, const float* __restrict__ beta,
    float* __restrict__ v_t) {
  __shared__ float4 red[256];
  int t = threadIdx.x;
  int mloc = t & 63, grp = t >> 6;
  int m = blockIdx.x * 64 + mloc;
  const float4* P = (const float4*)partial;
  float4 s4 = make_float4(0.f, 0.f, 0.f, 0.f);
#pragma unroll 8
  for (int i = 0; i < 64; ++i) {
    int b = grp * 64 + i;
    float4 p = P[(size_t)b * NN + m];
    s4.x += p.x; s4.y += p.y; s4.z += p.z; s4.w += p.w;
  }
  red[t] = s4;
  __syncthreads();
  if (t < 64) {
    float4 a = red[t];
#pragma unroll
    for (int g = 1; g < 4; ++g) {
      float4 r = red[t + 64 * g];
      a.x += r.x; a.y += r.y; a.z += r.z; a.w += r.w;
    }
    int mm = blockIdx.x * 64 + t;
    float4 res;
    res.x = beta[0 * NN + mm] / a.x;
    res.y = beta[1 * NN + mm] / a.y;
    res.z = beta[2 * NN + mm] / a.z;
    res.w = beta[3 * NN + mm] / a.w;
    ((float4*)v_t)[mm] = res;
  }
}

// ---------------------------------------------------------------------------
// out: f[s][n] = eps*log(u[n][s]); g[s][m] = eps*log(v[m][s])  (f32)
__global__ __launch_bounds__(256) void finalize(
    const float* __restrict__ u_t, const float* __restrict__ v_t,
    const void* __restrict__ epsp, float* __restrict__ out) {
  int gid = blockIdx.x * 256 + threadIdx.x;
  float eps = read_eps(epsp);
  if (gid < NN) {
    float4 u = ((const float4*)u_t)[gid];
    out[0 * NN + gid] = eps * __logf(u.x);
    out[1 * NN + gid] = eps * __logf(u.y);
    out[2 * NN + gid] = eps * __logf(u.z);
    out[3 * NN + gid] = eps * __logf(u.w);
  } else {
    int m = gid - NN;
    float4 v = ((const float4*)v_t)[m];
    out[4 * NN + 0 * NN + m] = eps * __logf(v.x);
    out[4 * NN + 1 * NN + m] = eps * __logf(v.y);
    out[4 * NN + 2 * NN + m] = eps * __logf(v.z);
    out[4 * NN + 3 * NN + m] = eps * __logf(v.w);
  }
}

// ---------------------------------------------------------------------------
extern "C" void kernel_launch(void* const* d_in, const int* in_sizes, int n_in,
                              void* d_out, int out_size, void* d_ws, size_t ws_size,
                              hipStream_t stream) {
  (void)in_sizes; (void)n_in; (void)out_size; (void)ws_size;
  const float* alpha = (const float*)d_in[0];   // f32 (4,4096)
  const float* beta  = (const float*)d_in[1];   // f32 (4,4096)
  const float* C     = (const float*)d_in[2];   // f32 (4096,4096)
  const void*  epsp  = d_in[3];                 // f32 scalar

  char* ws = (char*)d_ws;
  unsigned short* K = (unsigned short*)ws;                         // 32 MiB
  float* partial    = (float*)(ws + 33554432);                     // 16 MiB
  float* u_t        = (float*)(ws + 33554432 + 16777216);          // 64 KiB
  float* v_t        = (float*)(ws + 33554432 + 16777216 + 65536);  // 64 KiB
  float* out = (float*)d_out;

  build_k<<<(NN * NN / 8) / 256, 256, 0, stream>>>(C, epsp, K, v_t);
  for (int it = 0; it < NITER; ++it) {
    iterate<<<NBLK, 256, 0, stream>>>(K, v_t, alpha, u_t, partial);
    reduceV<<<64, 256, 0, stream>>>(partial, beta, v_t);
  }
  finalize<<<2 * NN / 256, 256, 0, stream>>>(u_t, v_t, epsp, out);
}